// Round 5
// baseline (290.692 us; speedup 1.0000x reference)
//
#include <hip/hip_runtime.h>
#include <hip/hip_bf16.h>

// CausalGraphDiscovery on MI355X. f32 buffers holding bf16-rounded values.
// Round 5: SINGLE dispatch, 753 blocks x 256 threads:
//   bid 0       : graph chain (corr -> adjacency MLP -> adj/PM/HP), deep-unroll GEMVs
//   bid 1..240  : pair-score MLP (bid<=32 also produce avg partials + L3 weight warm)
//   bid 241..752: mech MLP on bf16 MFMA; pre-stages everything mask-independent,
//                 spins on PM flag, short masked tail.
// Co-residency guarantee (deadlock-free under ANY dispatch order): union LDS
// ~51 KB -> 3 blocks/CU, 768 slots >= 753 blocks; 3012 waves <= 8192.
//
// d_out (f32): [0,256) adj | [256,131328) predictions | [131328,131584) scores
// ws (f32): [b*272,+272) avg partials (b<32) | 8960 PM | 9200 HP | 9400 dummy
//           | 9600 flags (int): [0..31] avg-ready, [32] PM-ready

typedef __attribute__((ext_vector_type(8))) short bf16x8;
typedef __attribute__((ext_vector_type(4))) short bf16x4;
typedef __attribute__((ext_vector_type(4))) float f32x4;

#define DEV __device__ __forceinline__
DEV short f2bf(float f){ __hip_bfloat16 h = __float2bfloat16(f); short s; __builtin_memcpy(&s,&h,2); return s; }
DEV float bf2f(short s){ __hip_bfloat16 h; __builtin_memcpy(&h,&s,2); return __bfloat162float(h); }

#define WS_P1(b)   ((b)*272)
#define WS_PM      8960
#define WS_HP      9200
#define WS_DUMMY   9400
#define WS_FLAG    9600
#define FLAG_MAGIC 0x1357F00D

union SMem {
    struct {                      // graph / avg / pair blocks (~9.3 KB)
        float sh[2048];
        float av[16*17];
    } g;
    struct {                      // mech blocks (~51 KB -> 3 blocks/CU)
        short X[256*24];          // X bf16, row stride 24 (16B-aligned rows)
        short W2T[64*136];        // Wm2^T[j][h] bf16
        short H1[4*16*136];       // per-wave H1[s][h] bf16
        short W1[16*128];         // Wfull (k==v zeroed, mask NOT applied) bf16
        float B1[128];
        float B2[64];
        float W3[64];
        float PMk[17];            // per-k mask (PMk[v]=0), [16]=has_parents
    } m;
};

__global__ void __launch_bounds__(256) k_all(
    const float* __restrict__ data,
    const float* __restrict__ Ws1, const float* __restrict__ bs1,
    const float* __restrict__ Ws2, const float* __restrict__ bs2,
    const float* __restrict__ Ws3, const float* __restrict__ bs3,
    const float* __restrict__ Wm1, const float* __restrict__ bm1,
    const float* __restrict__ Wm2, const float* __restrict__ bm2,
    const float* __restrict__ Wm3, const float* __restrict__ bm3,
    const float* __restrict__ Wt1, const float* __restrict__ bt1,
    const float* __restrict__ Wt2, const float* __restrict__ bt2,
    float* __restrict__ wsf, float* __restrict__ out)
{
    __shared__ __align__(16) SMem sm;
    int tid = threadIdx.x, bid = blockIdx.x;
    int* flags = (int*)(wsf + WS_FLAG);

    // ================================================================ mech
    if (bid >= 241) {
        int vid = bid - 241;
        int v = vid >> 5, chunk = vid & 31;
        int gs0 = chunk * 256;

        // ---- pre-flag staging (mask-independent) ----
        for (int e = tid; e < 2048; e += 256) {      // Wfull raw (k==v row = 0)
            int k = e >> 7, h = e & 127;
            float val = 0.f;
            if (k != v) {
                int p = k - (k > v ? 1 : 0);
                val = Wm1[v*1920 + p*128 + h];
            }
            sm.m.W1[e] = f2bf(val);
        }
        for (int e = tid; e < 8192; e += 256) {      // Wm2^T -> bf16
            int h = e >> 6, j = e & 63;
            sm.m.W2T[j*136 + h] = f2bf(Wm2[v*8192 + e]);
        }
        for (int e = tid; e < 4096; e += 256) {      // X -> bf16 (lossless)
            int s = e >> 4, k = e & 15;
            sm.m.X[s*24 + k] = f2bf(data[gs0*16 + e]);
        }
        if (tid < 128) sm.m.B1[tid] = bm1[v*128 + tid];
        else if (tid < 192) sm.m.B2[tid - 128] = bm2[v*64 + tid - 128];
        else sm.m.W3[tid - 192] = Wm3[v*64 + tid - 192];
        float bm3v = bm3[v];
        __syncthreads();

        int lane = tid & 63, wid = tid >> 6;
        int c = lane & 15, q = lane >> 4;

        // mask-independent fragments (hide LDS latency behind the spin)
        bf16x8 b2r[16];
        #pragma unroll
        for (int jt = 0; jt < 4; ++jt)
            #pragma unroll
            for (int ks = 0; ks < 4; ++ks)
                b2r[jt*4 + ks] = *(const bf16x8*)&sm.m.W2T[(jt*16 + c)*136 + ks*32 + q*8];
        float w3c[4], b2c[4];
        #pragma unroll
        for (int jt = 0; jt < 4; ++jt) { w3c[jt] = sm.m.W3[jt*16 + c]; b2c[jt] = sm.m.B2[jt*16 + c]; }

        // ---- wait for parent mask ----
        while (__hip_atomic_load(&flags[32], __ATOMIC_ACQUIRE,
                                 __HIP_MEMORY_SCOPE_AGENT) != FLAG_MAGIC)
            __builtin_amdgcn_s_sleep(2);
        if (tid < 16) {
            int k = tid;
            sm.m.PMk[k] = (k == v) ? 0.f
                        : wsf[WS_PM + v*15 + k - (k > v ? 1 : 0)];
        }
        if (tid == 16) sm.m.PMk[16] = wsf[WS_HP + v];
        __syncthreads();
        float hp = sm.m.PMk[16];

        // masked A1 fragments: elem jj = Wfull[k=q*8+jj][h=ht*16+c] * PMk[k]
        bf16x8 a1[8];
        #pragma unroll
        for (int ht = 0; ht < 8; ++ht) {
            #pragma unroll
            for (int jj = 0; jj < 8; ++jj) {
                int k = q*8 + jj;
                float w = (k < 16) ? bf2f(sm.m.W1[k*128 + ht*16 + c]) * sm.m.PMk[k] : 0.f;
                a1[ht][jj] = f2bf(w);
            }
        }

        short* h1buf = sm.m.H1 + wid*16*136;
        for (int stl = 0; stl < 4; ++stl) {
            int st = wid*4 + stl;                    // 16-sample tile
            // layer 1: D'[h][s] = Wfull^T . X^T  (C/D: 4 contiguous h per lane)
            bf16x8 xb;
            #pragma unroll
            for (int i2 = 0; i2 < 8; ++i2) xb[i2] = 0;
            if (q < 2) xb = *(const bf16x8*)&sm.m.X[(st*16 + c)*24 + q*8];
            f32x4 c1[8];
            #pragma unroll
            for (int ht = 0; ht < 8; ++ht) c1[ht] = *(const f32x4*)&sm.m.B1[ht*16 + q*4];
            #pragma unroll
            for (int ht = 0; ht < 8; ++ht)
                c1[ht] = __builtin_amdgcn_mfma_f32_16x16x32_bf16(a1[ht], xb, c1[ht], 0, 0, 0);
            #pragma unroll
            for (int ht = 0; ht < 8; ++ht) {
                bf16x4 pk;
                #pragma unroll
                for (int r = 0; r < 4; ++r) pk[r] = f2bf(fmaxf(c1[ht][r], 0.f));
                *(bf16x4*)&h1buf[c*136 + ht*16 + q*4] = pk;
            }
            // layer 2: A = H1 rows, B = Wm2^T frags
            f32x4 c2[4];
            #pragma unroll
            for (int jt = 0; jt < 4; ++jt) {
                float bi = b2c[jt];
                c2[jt] = (f32x4){bi, bi, bi, bi};
            }
            #pragma unroll
            for (int ks = 0; ks < 4; ++ks) {
                bf16x8 a2 = *(const bf16x8*)&h1buf[c*136 + ks*32 + q*8];
                #pragma unroll
                for (int jt = 0; jt < 4; ++jt)
                    c2[jt] = __builtin_amdgcn_mfma_f32_16x16x32_bf16(a2, b2r[jt*4 + ks], c2[jt], 0, 0, 0);
            }
            // layer 3: dot with Wm3 + width-16 butterfly
            float part[4];
            #pragma unroll
            for (int r = 0; r < 4; ++r) part[r] = 0.f;
            #pragma unroll
            for (int jt = 0; jt < 4; ++jt)
                #pragma unroll
                for (int r = 0; r < 4; ++r)
                    part[r] = fmaf(fmaxf(c2[jt][r], 0.f), w3c[jt], part[r]);
            #pragma unroll
            for (int off = 1; off < 16; off <<= 1)
                #pragma unroll
                for (int r = 0; r < 4; ++r)
                    part[r] += __shfl_xor(part[r], off, 16);
            if (c == 0) {
                #pragma unroll
                for (int r = 0; r < 4; ++r) {
                    int s_loc = st*16 + q*4 + r;
                    float mech = part[r] + bm3v;
                    float xv = bf2f(sm.m.X[s_loc*24 + v]);
                    out[256 + (gs0 + s_loc)*16 + v] = (hp != 0.f) ? mech : xv;
                }
            }
        }
        return;
    }

    // ================================================================ pairs (+avg)
    if (bid != 0) {
        int p = bid - 1;                              // pair 0..239

        if (bid <= 32) {
            // ---- avg partials for corr (producer) ----
            int b = bid - 1;
            int sl = tid >> 4, vv = tid & 15;
            int s = b*16 + sl;
            float acc = 0.f;
            #pragma unroll
            for (int bt = 0; bt < 16; ++bt) acc += data[bt*8192 + s*16 + vv];
            sm.g.av[sl*17 + vv] = acc * (1.f/16.f);
            __syncthreads();
            {
                int i = tid >> 4, j = tid & 15;
                float p1 = 0.f;
                #pragma unroll
                for (int r = 0; r < 16; ++r) p1 += sm.g.av[r*17 + i] * sm.g.av[r*17 + j];
                wsf[WS_P1(b) + tid] = p1;
            }
            if (tid < 16) {
                float ms = 0.f;
                #pragma unroll
                for (int r = 0; r < 16; ++r) ms += sm.g.av[r*17 + tid];
                wsf[WS_P1(b) + 256 + tid] = ms;
            }
            __syncthreads();
            if (tid == 0) {
                __threadfence();
                __hip_atomic_store(&flags[b], FLAG_MAGIC,
                                   __ATOMIC_RELEASE, __HIP_MEMORY_SCOPE_AGENT);
            }
            // ---- L3 weight warm for graph block (after flag; 16 KB/block) ----
            unsigned xr = 0;
            {
                const uint4* w1 = (const uint4*)Ws1;   // 16384 uint4 total
                uint4 u = w1[b*512 + tid];        xr ^= u.x^u.y^u.z^u.w;
                uint4 u2 = w1[b*512 + 256 + tid]; xr ^= u2.x^u2.y^u2.z^u2.w;
                const uint4* w2 = (const uint4*)Ws2;   // 8192 uint4
                uint4 u3 = w2[b*256 + tid];       xr ^= u3.x^u3.y^u3.z^u3.w;
                const uint4* w3 = (const uint4*)Ws3;   // 8192 uint4
                uint4 u4 = w3[b*256 + tid];       xr ^= u4.x^u4.y^u4.z^u4.w;
            }
            if (xr == 0x9E3779B9u) wsf[WS_DUMMY] = 0.f;   // defeat DCE
        }

        // ---- pair-score MLP ----
        int i = p / 15, jr = p % 15;
        int j = jr + (jr >= i ? 1 : 0);
        float* w0 = sm.g.sh;        float* w1 = sm.g.sh + 32;
        float* bb = sm.g.sh + 64;   float* w2 = sm.g.sh + 96;
        float* red = sm.g.sh + 128;
        if (tid < 32) {
            w0[tid] = Wt1[p*64 + tid];
            w1[tid] = Wt1[p*64 + 32 + tid];
            bb[tid] = bt1[p*32 + tid];
            w2[tid] = Wt2[p*32 + tid];
        }
        if (tid == 0) sm.g.sh[700] = bt2[p];
        __syncthreads();
        float b2s = sm.g.sh[700];
        float acc = 0.f;
        for (int it = 0; it < 32; ++it) {
            int s = it*256 + tid;
            float xa = data[s*16 + i];                // one 64B line per row
            float xb = data[s*16 + j];
            float z = b2s;
            #pragma unroll
            for (int h = 0; h < 32; ++h) {
                float t1 = fmaf(xa, w0[h], fmaf(xb, w1[h], bb[h]));
                z = fmaf(fmaxf(t1, 0.f), w2[h], z);
            }
            acc += 1.f / (1.f + expf(-z));
        }
        red[tid] = acc;
        __syncthreads();
        for (int off = 128; off > 0; off >>= 1) {
            if (tid < off) red[tid] += red[tid + off];
            __syncthreads();
        }
        if (tid == 0) out[256 + 131072 + i*16 + j] = red[0] * (1.f/8192.f);
        return;
    }

    // ================================================================ graph (bid 0)
    if (tid < 32) {
        while (__hip_atomic_load(&flags[tid], __ATOMIC_ACQUIRE,
                                 __HIP_MEMORY_SCOPE_AGENT) != FLAG_MAGIC)
            __builtin_amdgcn_s_sleep(2);
    }
    __syncthreads();
    __threadfence();

    float* corr_s = sm.g.sh;          float* part   = sm.g.sh + 256;
    float* h1_s   = sm.g.sh + 768;    float* h2_s   = sm.g.sh + 1024;
    float* adj_s  = sm.g.sh + 1152;   float* pm_s   = sm.g.sh + 1408;
    float* m_s    = sm.g.sh + 1648;   float* std_s  = sm.g.sh + 1664;
    float* cov_s  = sm.g.sh + 1680;

    {
        float p1 = 0.f;
        #pragma unroll 8
        for (int b = 0; b < 32; ++b) p1 += wsf[WS_P1(b) + tid];
        if (tid < 16) {
            float ms = 0.f;
            #pragma unroll 8
            for (int b = 0; b < 32; ++b) ms += wsf[WS_P1(b) + 256 + tid];
            m_s[tid] = ms * (1.f/512.f);
        }
        __syncthreads();
        int i = tid >> 4, j = tid & 15;
        cov_s[tid] = p1 - 512.f*m_s[i]*m_s[j];
    }
    __syncthreads();
    if (tid < 16) std_s[tid] = sqrtf(fmaxf(cov_s[tid*17], 0.f));
    __syncthreads();
    {
        int i = tid >> 4, j = tid & 15;
        float den = std_s[i]*std_s[j];
        corr_s[tid] = (den > 0.f && i != j) ? fabsf(cov_s[tid]/den) : 0.f;
    }
    __syncthreads();
    // layer1: h1[t] = relu(sum_i corr[i]*Ws1[i*256+t]); 32 loads in flight
    {
        float a0=0.f, a1=0.f, a2=0.f, a3=0.f;
        #pragma unroll 8
        for (int i = 0; i < 256; i += 4) {
            a0 = fmaf(corr_s[i  ], Ws1[(i  )*256 + tid], a0);
            a1 = fmaf(corr_s[i+1], Ws1[(i+1)*256 + tid], a1);
            a2 = fmaf(corr_s[i+2], Ws1[(i+2)*256 + tid], a2);
            a3 = fmaf(corr_s[i+3], Ws1[(i+3)*256 + tid], a3);
        }
        h1_s[tid] = fmaxf(a0+a1+a2+a3 + bs1[tid], 0.f);
    }
    __syncthreads();
    // layer2: K=256 split in 2 halves across 256 threads
    {
        int t = tid & 127, half = tid >> 7;
        const float* W2p = Ws2 + half*128*128;
        const float* h1p = h1_s + half*128;
        float a0=0.f, a1=0.f, a2=0.f, a3=0.f;
        #pragma unroll 8
        for (int i = 0; i < 128; i += 4) {
            a0 = fmaf(h1p[i  ], W2p[(i  )*128 + t], a0);
            a1 = fmaf(h1p[i+1], W2p[(i+1)*128 + t], a1);
            a2 = fmaf(h1p[i+2], W2p[(i+2)*128 + t], a2);
            a3 = fmaf(h1p[i+3], W2p[(i+3)*128 + t], a3);
        }
        part[half*128 + t] = a0+a1+a2+a3;
    }
    __syncthreads();
    if (tid < 128) h2_s[tid] = fmaxf(part[tid] + part[128 + tid] + bs2[tid], 0.f);
    __syncthreads();
    // layer3 + sigmoid + triu
    {
        float a0=0.f, a1=0.f, a2=0.f, a3=0.f;
        #pragma unroll 8
        for (int i = 0; i < 128; i += 4) {
            a0 = fmaf(h2_s[i  ], Ws3[(i  )*256 + tid], a0);
            a1 = fmaf(h2_s[i+1], Ws3[(i+1)*256 + tid], a1);
            a2 = fmaf(h2_s[i+2], Ws3[(i+2)*256 + tid], a2);
            a3 = fmaf(h2_s[i+3], Ws3[(i+3)*256 + tid], a3);
        }
        float z = a0+a1+a2+a3 + bs3[tid];
        float a = 1.f / (1.f + expf(-z));
        int r = tid >> 4, cc = tid & 15;
        float adjv = (r < cc) ? a : 0.f;              // triu(adj,1)
        adj_s[tid] = adjv;
        out[tid] = adjv;
    }
    __syncthreads();
    if (tid < 240) {
        int v = tid / 15, pr = tid % 15;
        int jj = pr + (pr >= v ? 1 : 0);
        float pmv = (adj_s[jj*16 + v] > 0.5f) ? 1.f : 0.f;
        wsf[WS_PM + tid] = pmv;
        pm_s[tid] = pmv;
    }
    if (tid < 16) out[256 + 131072 + tid*17] = 0.f;   // scores diagonal
    __syncthreads();
    if (tid < 16) {
        float sum = 0.f;
        #pragma unroll
        for (int pr = 0; pr < 15; ++pr) sum += pm_s[tid*15 + pr];
        wsf[WS_HP + tid] = (sum > 0.f) ? 1.f : 0.f;
    }
    __syncthreads();
    if (tid == 0) {
        __threadfence();
        __hip_atomic_store(&flags[32], FLAG_MAGIC,
                           __ATOMIC_RELEASE, __HIP_MEMORY_SCOPE_AGENT);
    }
}

// ---------------------------------------------------------------- launch
extern "C" void kernel_launch(void* const* d_in, const int* in_sizes, int n_in,
                              void* d_out, int out_size, void* d_ws, size_t ws_size,
                              hipStream_t stream)
{
    const float* data = (const float*)d_in[0];
    const float* Ws1  = (const float*)d_in[1];
    const float* bs1  = (const float*)d_in[2];
    const float* Ws2  = (const float*)d_in[3];
    const float* bs2  = (const float*)d_in[4];
    const float* Ws3  = (const float*)d_in[5];
    const float* bs3  = (const float*)d_in[6];
    const float* Wm1  = (const float*)d_in[7];
    const float* bm1  = (const float*)d_in[8];
    const float* Wm2  = (const float*)d_in[9];
    const float* bm2  = (const float*)d_in[10];
    const float* Wm3  = (const float*)d_in[11];
    const float* bm3  = (const float*)d_in[12];
    const float* Wt1  = (const float*)d_in[13];
    const float* bt1  = (const float*)d_in[14];
    const float* Wt2  = (const float*)d_in[15];
    const float* bt2  = (const float*)d_in[16];
    float* wsf = (float*)d_ws;
    float* out = (float*)d_out;

    hipLaunchKernelGGL(k_all, dim3(753), dim3(256), 0, stream,
                       data, Ws1, bs1, Ws2, bs2, Ws3, bs3,
                       Wm1, bm1, Wm2, bm2, Wm3, bm3,
                       Wt1, bt1, Wt2, bt2, wsf, out);
}

// Round 6
// 115.484 us; speedup vs baseline: 2.5172x; 2.5172x over previous
//
#include <hip/hip_runtime.h>
#include <hip/hip_bf16.h>

// CausalGraphDiscovery on MI355X. f32 buffers holding bf16-rounded values.
// Round 6: revert to round-4 two-dispatch structure (round-5 fusion's mass
// spin-wait caused memory-system congestion collapse: 205us kernel, 6% VALU).
//   k_main (241x512): block 0 graph chain (spin on 32 flags from blocks 1..32
//                     — ONE block polling is proven cheap); blocks 1..32 avg
//                     partials + L3 weight warm; blocks 1..240 pair MLP which
//                     now writes scores DIRECTLY to d_out.
//   k_mech (512x256): bf16-MFMA mech MLP (no scatter tail).
//
// d_out (f32): [0,256) adj | [256,131328) predictions | [131328,131584) scores
// ws (f32): [b*272,+272) avg partials (b<32) | 8960 PM | 9200 HP | 9400 dummy
//           | 9600 flags (int): [0..31] avg-ready

typedef __attribute__((ext_vector_type(8))) short bf16x8;
typedef __attribute__((ext_vector_type(4))) short bf16x4;
typedef __attribute__((ext_vector_type(4))) float f32x4;

#define DEV __device__ __forceinline__
DEV short f2bf(float f){ __hip_bfloat16 h = __float2bfloat16(f); short s; __builtin_memcpy(&s,&h,2); return s; }
DEV float bf2f(short s){ __hip_bfloat16 h; __builtin_memcpy(&h,&s,2); return __bfloat162float(h); }

#define WS_P1(b)   ((b)*272)
#define WS_PM      8960
#define WS_HP      9200
#define WS_DUMMY   9400
#define WS_FLAG    9600
#define FLAG_MAGIC 0x1357F00D

// ---------------------------------------------------------------- kernel 1
__global__ void __launch_bounds__(512) k_main(
    const float* __restrict__ data,
    const float* __restrict__ Ws1, const float* __restrict__ bs1,
    const float* __restrict__ Ws2, const float* __restrict__ bs2,
    const float* __restrict__ Ws3, const float* __restrict__ bs3,
    const float* __restrict__ Wt1, const float* __restrict__ bt1,
    const float* __restrict__ Wt2, const float* __restrict__ bt2,
    float* __restrict__ wsf, float* __restrict__ out)
{
    __shared__ float sh[2048];
    __shared__ float av[16*17];
    int tid = threadIdx.x;
    int* flags = (int*)(wsf + WS_FLAG);

    if (blockIdx.x != 0) {
        int p = blockIdx.x - 1;      // pair index 0..239

        if (blockIdx.x <= 32) {
            // ---- producer: avg partials over samples b*16..b*16+15 ----
            int b = blockIdx.x - 1;
            if (tid < 256) {
                int sl = tid >> 4, vv = tid & 15;
                int s = b*16 + sl;
                float acc = 0.f;
                #pragma unroll
                for (int bt = 0; bt < 16; ++bt) acc += data[bt*8192 + s*16 + vv];
                av[sl*17 + vv] = acc * (1.f/16.f);
            }
            __syncthreads();
            if (tid < 256) {
                int i = tid >> 4, j = tid & 15;
                float p1 = 0.f;
                #pragma unroll
                for (int r = 0; r < 16; ++r) p1 += av[r*17 + i] * av[r*17 + j];
                wsf[WS_P1(b) + tid] = p1;
            }
            if (tid < 16) {
                float ms = 0.f;
                #pragma unroll
                for (int r = 0; r < 16; ++r) ms += av[r*17 + tid];
                wsf[WS_P1(b) + 256 + tid] = ms;
            }
            __syncthreads();
            if (tid == 0) {
                __threadfence();
                __hip_atomic_store(&flags[b], FLAG_MAGIC,
                                   __ATOMIC_RELEASE, __HIP_MEMORY_SCOPE_AGENT);
            }
            // ---- L3 weight warm (32 blocks x 16 KB = all of Ws1/Ws2/Ws3) ----
            unsigned xr = 0;
            { uint4 u = ((const uint4*)Ws1)[b*512 + tid]; xr ^= u.x^u.y^u.z^u.w; }
            if (tid < 256) { uint4 u = ((const uint4*)Ws2)[b*256 + tid];       xr ^= u.x^u.y^u.z^u.w; }
            else           { uint4 u = ((const uint4*)Ws3)[b*256 + tid - 256]; xr ^= u.x^u.y^u.z^u.w; }
            if (xr == 0x9E3779B9u) wsf[WS_DUMMY] = 0.f;   // defeat DCE
        }

        // ---- pair MLP for pair p; writes scores cell directly ----
        int i = p / 15, jr = p % 15;
        int j = jr + (jr >= i ? 1 : 0);
        float* w0 = sh;        float* w1 = sh + 32;
        float* bb = sh + 64;   float* w2 = sh + 96;
        float* red = sh + 128;
        if (tid < 32) {
            w0[tid] = Wt1[p*64 + tid];
            w1[tid] = Wt1[p*64 + 32 + tid];
            bb[tid] = bt1[p*32 + tid];
            w2[tid] = Wt2[p*32 + tid];
        }
        if (tid == 0) sh[700] = bt2[p];
        __syncthreads();
        float b2s = sh[700];
        float acc = 0.f;
        for (int it = 0; it < 16; ++it) {
            int s = it*512 + tid;
            float xa = data[s*16 + i];    // row = one 64B line; xb hits L1
            float xb = data[s*16 + j];
            float z = b2s;
            #pragma unroll
            for (int h = 0; h < 32; ++h) {
                float t1 = fmaf(xa, w0[h], fmaf(xb, w1[h], bb[h]));
                z = fmaf(fmaxf(t1, 0.f), w2[h], z);
            }
            acc += 1.f / (1.f + expf(-z));
        }
        red[tid] = acc;
        __syncthreads();
        for (int off = 256; off > 0; off >>= 1) {
            if (tid < off) red[tid] += red[tid + off];
            __syncthreads();
        }
        if (tid == 0) out[256 + 131072 + i*16 + j] = red[0] * (1.f/8192.f);
        return;
    }

    // ---- graph block (block 0): 32 threads poll — cheap, proven in r4 ----
    if (tid < 32) {
        while (__hip_atomic_load(&flags[tid], __ATOMIC_ACQUIRE,
                                 __HIP_MEMORY_SCOPE_AGENT) != FLAG_MAGIC)
            __builtin_amdgcn_s_sleep(8);
    }
    __syncthreads();
    __threadfence();

    float* corr_s = sh;          float* part   = sh + 256;
    float* h1_s   = sh + 768;    float* h2_s   = sh + 1024;
    float* adj_s  = sh + 1152;   float* pm_s   = sh + 1408;
    float* m_s    = sh + 1648;   float* std_s  = sh + 1664;
    float* cov_s  = sh + 1680;

    float p1 = 0.f;
    if (tid < 256) {
        #pragma unroll 8
        for (int b = 0; b < 32; ++b) p1 += wsf[WS_P1(b) + tid];
    }
    if (tid < 16) {
        float ms = 0.f;
        #pragma unroll 8
        for (int b = 0; b < 32; ++b) ms += wsf[WS_P1(b) + 256 + tid];
        m_s[tid] = ms * (1.f/512.f);
    }
    __syncthreads();
    if (tid < 256) { int i = tid>>4, j = tid&15; cov_s[tid] = p1 - 512.f*m_s[i]*m_s[j]; }
    __syncthreads();
    if (tid < 16) std_s[tid] = sqrtf(fmaxf(cov_s[tid*17], 0.f));
    __syncthreads();
    if (tid < 256) {
        int i = tid>>4, j = tid&15;
        float den = std_s[i]*std_s[j];
        corr_s[tid] = (den > 0.f && i != j) ? fabsf(cov_s[tid]/den) : 0.f;
    }
    __syncthreads();
    {   // layer1: 256 outputs, K=256 split in 2; 4 accumulators -> 16 in flight
        int t = tid & 255, half = tid >> 8;
        const float* W1p = Ws1 + half*128*256;
        const float* cp  = corr_s + half*128;
        float a0=0.f, a1=0.f, a2=0.f, a3=0.f;
        #pragma unroll 8
        for (int i = 0; i < 128; i += 4) {
            a0 = fmaf(cp[i  ], W1p[(i  )*256 + t], a0);
            a1 = fmaf(cp[i+1], W1p[(i+1)*256 + t], a1);
            a2 = fmaf(cp[i+2], W1p[(i+2)*256 + t], a2);
            a3 = fmaf(cp[i+3], W1p[(i+3)*256 + t], a3);
        }
        part[half*256 + t] = a0+a1+a2+a3;
    }
    __syncthreads();
    if (tid < 256) h1_s[tid] = fmaxf(part[tid] + part[256 + tid] + bs1[tid], 0.f);
    __syncthreads();
    {   // layer2: 128 outputs, K=256 split in 4
        int t = tid & 127, qq = tid >> 7;
        const float* W2p = Ws2 + qq*64*128;
        const float* h1p = h1_s + qq*64;
        float a0=0.f, a1=0.f, a2=0.f, a3=0.f;
        #pragma unroll 4
        for (int i = 0; i < 64; i += 4) {
            a0 = fmaf(h1p[i  ], W2p[(i  )*128 + t], a0);
            a1 = fmaf(h1p[i+1], W2p[(i+1)*128 + t], a1);
            a2 = fmaf(h1p[i+2], W2p[(i+2)*128 + t], a2);
            a3 = fmaf(h1p[i+3], W2p[(i+3)*128 + t], a3);
        }
        part[qq*128 + t] = a0+a1+a2+a3;
    }
    __syncthreads();
    if (tid < 128)
        h2_s[tid] = fmaxf(part[tid] + part[128+tid] + part[256+tid] + part[384+tid] + bs2[tid], 0.f);
    __syncthreads();
    {   // layer3: 256 outputs, K=128 split in 2
        int t = tid & 255, half = tid >> 8;
        const float* W3p = Ws3 + half*64*256;
        const float* h2p = h2_s + half*64;
        float a0=0.f, a1=0.f, a2=0.f, a3=0.f;
        #pragma unroll 4
        for (int i = 0; i < 64; i += 4) {
            a0 = fmaf(h2p[i  ], W3p[(i  )*256 + t], a0);
            a1 = fmaf(h2p[i+1], W3p[(i+1)*256 + t], a1);
            a2 = fmaf(h2p[i+2], W3p[(i+2)*256 + t], a2);
            a3 = fmaf(h2p[i+3], W3p[(i+3)*256 + t], a3);
        }
        part[half*256 + t] = a0+a1+a2+a3;
    }
    __syncthreads();
    if (tid < 256) {
        float z = part[tid] + part[256 + tid] + bs3[tid];
        float a = 1.f / (1.f + expf(-z));
        int r = tid >> 4, cc = tid & 15;
        float adjv = (r < cc) ? a : 0.f;     // triu(adj,1)
        adj_s[tid] = adjv;
        out[tid] = adjv;
    }
    __syncthreads();
    if (tid < 240) {
        int v = tid / 15, pr = tid % 15;
        int jj = pr + (pr >= v ? 1 : 0);
        float pmv = (adj_s[jj*16 + v] > 0.5f) ? 1.f : 0.f;
        wsf[WS_PM + tid] = pmv;
        pm_s[tid] = pmv;
    }
    if (tid >= 256 && tid < 272) out[256 + 131072 + (tid-256)*17] = 0.f;  // scores diag
    __syncthreads();
    if (tid < 16) {
        float sum = 0.f;
        #pragma unroll
        for (int pr = 0; pr < 15; ++pr) sum += pm_s[tid*15 + pr];
        wsf[WS_HP + tid] = (sum > 0.f) ? 1.f : 0.f;
    }
}

// ---------------------------------------------------------------- kernel 2
// 512 blocks: (v=bid>>5, 256-sample chunk) mech MLP on bf16 MFMA.
__global__ void __launch_bounds__(256, 2) k_mech(
    const float* __restrict__ data,
    const float* __restrict__ Wm1, const float* __restrict__ bm1,
    const float* __restrict__ Wm2, const float* __restrict__ bm2,
    const float* __restrict__ Wm3, const float* __restrict__ bm3,
    const float* __restrict__ wsf, float* __restrict__ out)
{
    int tid = threadIdx.x, bid = blockIdx.x;
    int v = bid >> 5, chunk = bid & 31;
    int gs0 = chunk * 256;

    __shared__ __align__(16) short smX[256*24];
    __shared__ __align__(16) short smW2T[64*136];
    __shared__ __align__(16) short smH1[4][16*136];
    __shared__ __align__(16) float smW1[16*128];
    __shared__ __align__(16) float smB1[128];
    __shared__ float smB2[64];
    __shared__ float smW3[64];

    for (int e = tid; e < 2048; e += 256) {          // Wfull (mask+self folded)
        int k = e >> 7, h = e & 127;
        float val = 0.f;
        if (k != v) {
            int p = k - (k > v ? 1 : 0);
            val = Wm1[v*1920 + p*128 + h] * wsf[WS_PM + v*15 + p];
        }
        smW1[e] = val;
    }
    for (int e = tid; e < 8192; e += 256) {          // Wm2^T -> bf16
        int h = e >> 6, j = e & 63;
        smW2T[j*136 + h] = f2bf(Wm2[v*8192 + e]);
    }
    for (int e = tid; e < 4096; e += 256) {          // X -> bf16 (lossless)
        int s = e >> 4, k = e & 15;
        smX[s*24 + k] = f2bf(data[gs0*16 + e]);
    }
    if (tid < 128) smB1[tid] = bm1[v*128 + tid];
    else if (tid < 192) smB2[tid - 128] = bm2[v*64 + tid - 128];
    else smW3[tid - 192] = Wm3[v*64 + tid - 192];
    __syncthreads();

    int lane = tid & 63, wid = tid >> 6;
    int c = lane & 15, q = lane >> 4;
    float hp = wsf[WS_HP + v];
    float bm3v = bm3[v];

    bf16x8 a1[8];
    #pragma unroll
    for (int ht = 0; ht < 8; ++ht) {
        #pragma unroll
        for (int jj = 0; jj < 8; ++jj) {
            int k = q*8 + jj;
            float w = (k < 16) ? smW1[k*128 + ht*16 + c] : 0.f;
            a1[ht][jj] = f2bf(w);
        }
    }
    bf16x8 b2r[16];
    #pragma unroll
    for (int jt = 0; jt < 4; ++jt)
        #pragma unroll
        for (int ks = 0; ks < 4; ++ks)
            b2r[jt*4 + ks] = *(const bf16x8*)&smW2T[(jt*16 + c)*136 + ks*32 + q*8];
    float w3c[4], b2c[4];
    #pragma unroll
    for (int jt = 0; jt < 4; ++jt) { w3c[jt] = smW3[jt*16 + c]; b2c[jt] = smB2[jt*16 + c]; }

    short* h1buf = smH1[wid];

    for (int stl = 0; stl < 4; ++stl) {
        int st = wid*4 + stl;
        bf16x8 xb;
        #pragma unroll
        for (int i2 = 0; i2 < 8; ++i2) xb[i2] = 0;
        if (q < 2) xb = *(const bf16x8*)&smX[(st*16 + c)*24 + q*8];
        f32x4 c1[8];
        #pragma unroll
        for (int ht = 0; ht < 8; ++ht) c1[ht] = *(const f32x4*)&smB1[ht*16 + q*4];
        #pragma unroll
        for (int ht = 0; ht < 8; ++ht)
            c1[ht] = __builtin_amdgcn_mfma_f32_16x16x32_bf16(a1[ht], xb, c1[ht], 0, 0, 0);
        #pragma unroll
        for (int ht = 0; ht < 8; ++ht) {
            bf16x4 pk;
            #pragma unroll
            for (int r = 0; r < 4; ++r) pk[r] = f2bf(fmaxf(c1[ht][r], 0.f));
            *(bf16x4*)&h1buf[c*136 + ht*16 + q*4] = pk;
        }
        f32x4 c2[4];
        #pragma unroll
        for (int jt = 0; jt < 4; ++jt) {
            float bi = b2c[jt];
            c2[jt] = (f32x4){bi, bi, bi, bi};
        }
        #pragma unroll
        for (int ks = 0; ks < 4; ++ks) {
            bf16x8 a2 = *(const bf16x8*)&h1buf[c*136 + ks*32 + q*8];
            #pragma unroll
            for (int jt = 0; jt < 4; ++jt)
                c2[jt] = __builtin_amdgcn_mfma_f32_16x16x32_bf16(a2, b2r[jt*4 + ks], c2[jt], 0, 0, 0);
        }
        float part[4];
        #pragma unroll
        for (int r = 0; r < 4; ++r) part[r] = 0.f;
        #pragma unroll
        for (int jt = 0; jt < 4; ++jt)
            #pragma unroll
            for (int r = 0; r < 4; ++r)
                part[r] = fmaf(fmaxf(c2[jt][r], 0.f), w3c[jt], part[r]);
        #pragma unroll
        for (int off = 1; off < 16; off <<= 1)
            #pragma unroll
            for (int r = 0; r < 4; ++r)
                part[r] += __shfl_xor(part[r], off, 16);
        if (c == 0) {
            #pragma unroll
            for (int r = 0; r < 4; ++r) {
                int s_loc = st*16 + q*4 + r;
                float mech = part[r] + bm3v;
                float xv = bf2f(smX[s_loc*24 + v]);
                out[256 + (gs0 + s_loc)*16 + v] = (hp != 0.f) ? mech : xv;
            }
        }
    }
}

// ---------------------------------------------------------------- launch
extern "C" void kernel_launch(void* const* d_in, const int* in_sizes, int n_in,
                              void* d_out, int out_size, void* d_ws, size_t ws_size,
                              hipStream_t stream)
{
    const float* data = (const float*)d_in[0];
    const float* Ws1  = (const float*)d_in[1];
    const float* bs1  = (const float*)d_in[2];
    const float* Ws2  = (const float*)d_in[3];
    const float* bs2  = (const float*)d_in[4];
    const float* Ws3  = (const float*)d_in[5];
    const float* bs3  = (const float*)d_in[6];
    const float* Wm1  = (const float*)d_in[7];
    const float* bm1  = (const float*)d_in[8];
    const float* Wm2  = (const float*)d_in[9];
    const float* bm2  = (const float*)d_in[10];
    const float* Wm3  = (const float*)d_in[11];
    const float* bm3  = (const float*)d_in[12];
    const float* Wt1  = (const float*)d_in[13];
    const float* bt1  = (const float*)d_in[14];
    const float* Wt2  = (const float*)d_in[15];
    const float* bt2  = (const float*)d_in[16];
    float* wsf = (float*)d_ws;
    float* out = (float*)d_out;

    hipLaunchKernelGGL(k_main, dim3(241), dim3(512), 0, stream,
                       data, Ws1, bs1, Ws2, bs2, Ws3, bs3,
                       Wt1, bt1, Wt2, bt2, wsf, out);
    hipLaunchKernelGGL(k_mech, dim3(512), dim3(256), 0, stream,
                       data, Wm1, bm1, Wm2, bm2, Wm3, bm3, wsf, out);
}